// Round 4
// baseline (290.779 us; speedup 1.0000x reference)
//
#include <hip/hip_runtime.h>
#include <math.h>

typedef unsigned short u16;
typedef unsigned int   u32;

typedef __attribute__((ext_vector_type(8))) _Float16 f16x8;
typedef __attribute__((ext_vector_type(4))) float    f32x4;

// ---------- constants ----------
#define NB   2
#define C    256
#define H    96
#define W    96
#define HW   (H*W)          // 9216
#define HP   98
#define OC   256
#define KDIM (9*C)          // 2304
#define NS   (NB*HW)        // 18432 spatial columns

// ws layout (bytes)
#define XP_OFF    0                      // 2*98*98*256 fp32 = 19668992
#define AHI_OFF   19668992               // 256*2304 f16     = 1179648
#define ALO_OFF   20848640               // 256*2304 f16     = 1179648
#define A2HI_OFF  22028288               // 32*2304 f16      = 147456
#define A2LO_OFF  22175744               // 32*2304 f16      = 147456
#define OFF2_OFF  22323200               // 21*18432 fp32    = 1548288
#define IDX_OFF   23871488               // 9*18432*4 int    = 2654208
#define G_OFF     26525696               // 9*18432*4 fp32   = 2654208
// end 29179904

__device__ __forceinline__ u16 h2u(_Float16 h) {
  return __builtin_bit_cast(unsigned short, h);
}
__device__ __forceinline__ void split16(float v, u16& hi, u16& lo) {
  _Float16 h = (_Float16)v;        // v_cvt_f16_f32, RNE
  float r = v - (float)h;          // exact residual
  _Float16 l = (_Float16)r;
  hi = h2u(h); lo = h2u(l);
}
// LDS-only barrier: waits lgkmcnt(0) but does NOT drain vmcnt.
__device__ __forceinline__ void sync_lds() {
  asm volatile("s_waitcnt lgkmcnt(0)\n\ts_barrier" ::: "memory");
}

// build split-f16 B row (8 weighted-gathered channels) and write to LDS buffer.
// T = float4[8] taps {t0a,t0b,t1a,t1b,t2a,t2b,t3a,t3b}, G = float4 bilinear weights.
#define BW_GATHER(T, G, BUFI) do { \
  float v0_ = (G).x*(T)[0].x + (G).y*(T)[2].x + (G).z*(T)[4].x + (G).w*(T)[6].x; \
  float v1_ = (G).x*(T)[0].y + (G).y*(T)[2].y + (G).z*(T)[4].y + (G).w*(T)[6].y; \
  float v2_ = (G).x*(T)[0].z + (G).y*(T)[2].z + (G).z*(T)[4].z + (G).w*(T)[6].z; \
  float v3_ = (G).x*(T)[0].w + (G).y*(T)[2].w + (G).z*(T)[4].w + (G).w*(T)[6].w; \
  float v4_ = (G).x*(T)[1].x + (G).y*(T)[3].x + (G).z*(T)[5].x + (G).w*(T)[7].x; \
  float v5_ = (G).x*(T)[1].y + (G).y*(T)[3].y + (G).z*(T)[5].y + (G).w*(T)[7].y; \
  float v6_ = (G).x*(T)[1].z + (G).y*(T)[3].z + (G).z*(T)[5].z + (G).w*(T)[7].z; \
  float v7_ = (G).x*(T)[1].w + (G).y*(T)[3].w + (G).z*(T)[5].w + (G).w*(T)[7].w; \
  u16 h0_,l0_,h1_,l1_,h2_,l2_,h3_,l3_,h4_,l4_,h5_,l5_,h6_,l6_,h7_,l7_; \
  split16(v0_,h0_,l0_); split16(v1_,h1_,l1_); split16(v2_,h2_,l2_); split16(v3_,h3_,l3_); \
  split16(v4_,h4_,l4_); split16(v5_,h5_,l5_); split16(v6_,h6_,l6_); split16(v7_,h7_,l7_); \
  uint4 bph_, bpl_; \
  bph_.x = (u32)h0_ | ((u32)h1_ << 16); bph_.y = (u32)h2_ | ((u32)h3_ << 16); \
  bph_.z = (u32)h4_ | ((u32)h5_ << 16); bph_.w = (u32)h6_ | ((u32)h7_ << 16); \
  bpl_.x = (u32)l0_ | ((u32)l1_ << 16); bpl_.y = (u32)l2_ | ((u32)l3_ << 16); \
  bpl_.z = (u32)l4_ | ((u32)l5_ << 16); bpl_.w = (u32)l6_ | ((u32)l7_ << 16); \
  *(uint4*)(&Bh[BUFI][s_l*40 + cs]) = bph_; \
  *(uint4*)(&Bl[BUFI][s_l*40 + cs]) = bpl_; \
} while (0)

// same but raw taps (conv path): TA/TB = two contiguous float4 (8 channels)
#define BW_RAW(TA, TB, BUFI) do { \
  u16 h0_,l0_,h1_,l1_,h2_,l2_,h3_,l3_,h4_,l4_,h5_,l5_,h6_,l6_,h7_,l7_; \
  split16((TA).x,h0_,l0_); split16((TA).y,h1_,l1_); split16((TA).z,h2_,l2_); split16((TA).w,h3_,l3_); \
  split16((TB).x,h4_,l4_); split16((TB).y,h5_,l5_); split16((TB).z,h6_,l6_); split16((TB).w,h7_,l7_); \
  uint4 bph_, bpl_; \
  bph_.x = (u32)h0_ | ((u32)h1_ << 16); bph_.y = (u32)h2_ | ((u32)h3_ << 16); \
  bph_.z = (u32)h4_ | ((u32)h5_ << 16); bph_.w = (u32)h6_ | ((u32)h7_ << 16); \
  bpl_.x = (u32)l0_ | ((u32)l1_ << 16); bpl_.y = (u32)l2_ | ((u32)l3_ << 16); \
  bpl_.z = (u32)l4_ | ((u32)l5_ << 16); bpl_.w = (u32)l6_ | ((u32)l7_ << 16); \
  *(uint4*)(&Bh[BUFI][s_l*40 + cs]) = bph_; \
  *(uint4*)(&Bl[BUFI][s_l*40 + cs]) = bpl_; \
} while (0)

// ================= prep: pad_pack(0..1151) | pack_A(1152..1439) | pack_A2(1440..1475) =================
__global__ __launch_bounds__(256) void prep1(
    const float* __restrict__ x, const float* __restrict__ w_p,
    const float* __restrict__ w_ad, const float* __restrict__ w_conv,
    float* __restrict__ xp,
    u16* __restrict__ A_hi, u16* __restrict__ A_lo,
    u16* __restrict__ A2_hi, u16* __restrict__ A2_lo) {
  __shared__ float smem[64*65];
  int bx = blockIdx.x;
  int tid = threadIdx.x;

  if (bx < 1152) {
    // ---- NCHW fp32 -> padded NHWC fp32 (borders pre-zeroed by memset) ----
    int pb = bx;
    int n = pb / 576; int r = pb % 576;
    int cb = r / 144; int hwb = r % 144;
    int c0 = cb * 64, hw0 = hwb * 64;
    int ii = tid & 63; int cl4 = tid >> 6;
    #pragma unroll
    for (int r2 = 0; r2 < 16; r2++) {
      int c_l = cl4*16 + r2;
      smem[c_l*65 + ii] = x[(size_t)(n*C + c0 + c_l)*HW + hw0 + ii];
    }
    __syncthreads();
    int hw = hw0 + ii;
    int h = hw / W, w = hw % W;
    float* dst = xp + ((size_t)(n*HP + h + 1)*HP + (w + 1))*C + c0 + cl4*16;
    #pragma unroll
    for (int q = 0; q < 4; q++) {
      *(float4*)(dst + q*4) = make_float4(smem[(cl4*16 + q*4 + 0)*65 + ii],
                                          smem[(cl4*16 + q*4 + 1)*65 + ii],
                                          smem[(cl4*16 + q*4 + 2)*65 + ii],
                                          smem[(cl4*16 + q*4 + 3)*65 + ii]);
    }

  } else if (bx < 1440) {
    // ---- pack+split w_conv into MFMA-fragment-tiled A_hi/A_lo (r8/r9-proven) ----
    int pb = bx - 1152;                 // 0..287
    int t = pb*256 + tid;               // 0..73727
    int e0 = t*8;
    int lane = (e0 >> 3) & 63;
    int mi   = (e0 >> 9) & 3;
    int mw   = (e0 >> 11) & 1;
    int rr   = e0 >> 12; int itg = rr % 72; int mo = rr / 72;
    int o = mo*128 + mw*64 + mi*16 + (lane & 15);
    int kcb = itg*32 + (lane >> 4)*8;
    #pragma unroll
    for (int j2 = 0; j2 < 8; j2++) {
      int kc = kcb + j2; int k = kc >> 8; int c = kc & 255;
      float a = w_conv[((size_t)o*C + c)*9 + k];
      u16 hi, lo; split16(a, hi, lo);
      A_hi[e0 + j2] = hi; A_lo[e0 + j2] = lo;
    }

  } else {
    // ---- pack+split stage-A weights into frag-tiled A2 (M=32) ----
    int pb = bx - 1440;                 // 0..35
    int t = pb*256 + tid;               // 0..9215
    int e0 = t*8;
    int lane = (e0 >> 3) & 63;
    int mi   = (e0 >> 9) & 1;
    int itg  = e0 >> 10;                // 0..71
    int o = mi*16 + (lane & 15);
    int kcb = itg*32 + (lane >> 4)*8;
    #pragma unroll
    for (int j2 = 0; j2 < 8; j2++) {
      int kc = kcb + j2; int tap = kc >> 8; int c = kc & 255;
      float a = 0.f;
      if (o < 18)       a = w_p [((size_t)o*C + c)*9 + tap];
      else if (o < 21)  a = w_ad[((size_t)(o-18)*C + c)*9 + tap];
      u16 hi, lo; split16(a, hi, lo);
      A2_hi[e0 + j2] = hi; A2_lo[e0 + j2] = lo;
    }
  }
}

// ================= stage-A conv as split-f16 MFMA, reg-prefetch pipelined =================
// grid 576 = xcd(8) x [kh(2) x sbl(36)]; split-K2 via atomicAdd into off2.
// LDS protocol IDENTICAL to the proven r9 kernel: build->write buf(it&1) -> sync -> read buf(it&1).
// Only change: it+1's global loads are issued between ds_read and MFMA, so their
// latency hides under the MFMA cluster and survives the lgkm-only barrier.
__global__ __launch_bounds__(256) void conv_mfma(
    const u16* __restrict__ A2_hi, const u16* __restrict__ A2_lo,
    const float* __restrict__ xp, float* __restrict__ off2) {
  __shared__ u16 Bh[2][64*40];
  __shared__ u16 Bl[2][64*40];
  int bx = blockIdx.x;
  int xcd = bx & 7; int jj = bx >> 3;          // jj 0..71
  int kh = jj & 1; int sbl = jj >> 1;          // sbl 0..35
  int sb = xcd*36 + sbl;                       // 0..287
  int s0 = sb * 64;
  int tid = threadIdx.x;
  int wave = tid >> 6, lane = tid & 63;
  int l16 = lane & 15, quad = lane >> 4;

  f32x4 acc[2];
  f32x4 z4 = {0.f, 0.f, 0.f, 0.f};
  acc[0] = z4; acc[1] = z4;

  int s_l = tid >> 2; int cs = (tid & 3) * 8;  // B-build map (r7-r9 proven)
  int sg = s0 + s_l;
  int n = sg / HW; int hw = sg % HW;
  int h = hw / W, w = hw % W;
  const float* sbase = xp + ((size_t)(n*HP + h)*HP + w)*C;   // padded top-left

  const int itbase = kh*36;
  uint4 aH[2], aL[2];
  float4 tca, tcb;
  // ---- prologue: load regs for it 0 ----
  {
    int itg = itbase;
    #pragma unroll
    for (int mi = 0; mi < 2; mi++) {
      size_t off = ((size_t)(itg*2 + mi) << 9) + lane*8;
      aH[mi] = *(const uint4*)(A2_hi + off);
      aL[mi] = *(const uint4*)(A2_lo + off);
    }
    int tap = itg >> 3; int di = tap / 3, dj = tap % 3;
    int c0k = (itg & 7) * 32;
    const float* p0 = sbase + (di*HP + dj)*C + c0k + cs;
    tca = *(const float4*)(p0); tcb = *(const float4*)(p0 + 4);
  }

  #pragma unroll 2
  for (int it = 0; it < 36; it++) {
    int buf = it & 1;
    // ---- build current B tile from regs, write LDS (proven protocol) ----
    BW_RAW(tca, tcb, buf);
    sync_lds();
    // ---- ds_read current ----
    int rr = (wave*16 + l16)*40 + quad*8;
    f16x8 bfh = *(const f16x8*)(&Bh[buf][rr]);
    f16x8 bfl = *(const f16x8*)(&Bl[buf][rr]);
    // ---- issue it+1 loads (in flight under MFMA; survive lgkm-only barrier) ----
    uint4 aHn[2], aLn[2]; float4 tna, tnb;
    if (it < 35) {
      int itn = itbase + it + 1;
      #pragma unroll
      for (int mi = 0; mi < 2; mi++) {
        size_t off = ((size_t)(itn*2 + mi) << 9) + lane*8;
        aHn[mi] = *(const uint4*)(A2_hi + off);
        aLn[mi] = *(const uint4*)(A2_lo + off);
      }
      int tap = itn >> 3; int di = tap / 3, dj = tap % 3;
      int c0k = (itn & 7) * 32;
      const float* p0 = sbase + (di*HP + dj)*C + c0k + cs;
      tna = *(const float4*)(p0); tnb = *(const float4*)(p0 + 4);
    }
    // ---- MFMA ----
    #pragma unroll
    for (int mi = 0; mi < 2; mi++) {
      f16x8 fh = __builtin_bit_cast(f16x8, aH[mi]);
      f16x8 fl = __builtin_bit_cast(f16x8, aL[mi]);
      acc[mi] = __builtin_amdgcn_mfma_f32_16x16x32_f16(fh, bfh, acc[mi], 0, 0, 0);
      acc[mi] = __builtin_amdgcn_mfma_f32_16x16x32_f16(fh, bfl, acc[mi], 0, 0, 0);
      acc[mi] = __builtin_amdgcn_mfma_f32_16x16x32_f16(fl, bfh, acc[mi], 0, 0, 0);
    }
    // ---- rotate ----
    if (it < 35) {
      aH[0] = aHn[0]; aH[1] = aHn[1];
      aL[0] = aLn[0]; aL[1] = aLn[1];
      tca = tna; tcb = tnb;
    }
  }
  // ---- epilogue: rows <21 accumulate into off2 ----
  int sout = s0 + wave*16 + l16;
  #pragma unroll
  for (int mi = 0; mi < 2; mi++)
    #pragma unroll
    for (int rr2 = 0; rr2 < 4; rr2++) {
      int o = mi*16 + quad*4 + rr2;
      if (o < 21)
        atomicAdd(&off2[(size_t)o*NS + sout], acc[mi][rr2]);
    }
}

// ================= bilinear taps (reads off2 directly) =================
__global__ __launch_bounds__(256) void taps2(
    const float* __restrict__ off2, const float* __restrict__ b_p,
    const float* __restrict__ b_ad,
    int* __restrict__ idx_arr, float* __restrict__ g_arr) {
  int e = blockIdx.x * 256 + threadIdx.x;      // < 9*18432 = 165888
  int k = e / NS; int s = e % NS;
  int n = s / HW; int hw = s % HW;
  int h = hw / W, w = hw % W;
  float offx = off2[(size_t)k*NS + s]            + b_p[k];
  float offy = off2[(size_t)(k+9)*NS + s]        + b_p[k+9];
  float za   = off2[(size_t)(18 + (k%3))*NS + s] + b_ad[k % 3];
  float a2 = 2.0f / (1.0f + expf(za));         // (1-sigmoid)*DIL

  float ri = (float)(k / 3) - 1.0f, rj = (float)(k % 3) - 1.0f;
  float px = (float)(h + 1) + ri + offx + a2 * ri;
  float py = (float)(w + 1) + rj + offy + a2 * rj;
  float fx = floorf(px), fy = floorf(py);
  int qltx = min(max((int)fx, 0), 97);
  int qlty = min(max((int)fy, 0), 97);
  int qrbx = min(max((int)fx + 1, 0), 97);
  int qrby = min(max((int)fy + 1, 0), 97);
  bool mx = (px < 1.0f) || (px > 96.0f);
  bool my = (py < 1.0f) || (py > 96.0f);
  float pxm = mx ? fx : px;
  float pym = my ? fy : py;
  pxm = fminf(fmaxf(pxm, 0.f), 97.f);
  pym = fminf(fmaxf(pym, 0.f), 97.f);
  float glx = 1.0f + ((float)qltx - pxm);
  float grx = 1.0f - ((float)qrbx - pxm);
  float gly = 1.0f + ((float)qlty - pym);
  float gry = 1.0f - ((float)qrby - pym);
  int base = n * HP * HP * C;
  int4 qi;
  qi.x = base + (qltx*HP + qlty)*C;   // lt
  qi.y = base + (qrbx*HP + qrby)*C;   // rb
  qi.z = base + (qltx*HP + qrby)*C;   // lb
  qi.w = base + (qrbx*HP + qlty)*C;   // rt
  float4 gg = make_float4(glx*gly, grx*gry, glx*gry, grx*gly);
  *(int4*)(idx_arr + (size_t)e*4) = qi;
  *(float4*)(g_arr  + (size_t)e*4) = gg;
}

// ================= fused gather + split-f16 MFMA GEMM, M=256, reg-prefetch pipelined =================
// grid 576 = xcd(8) x [kh(2) x sbl(36)]; split-K2 via atomicAdd into out.
// LDS protocol IDENTICAL to the proven r9 kernel (build->write->sync->read, one barrier/iter).
// it+1's gathered-tap + A-frag loads are issued between ds_read and the MFMA cluster.
__global__ __launch_bounds__(256) void gemm_def(
    const u16* __restrict__ A_hi, const u16* __restrict__ A_lo,
    const float* __restrict__ xp,
    const int* __restrict__ idx_arr, const float* __restrict__ g_arr,
    float* __restrict__ out) {
  __shared__ u16 Bh[2][64*40];
  __shared__ u16 Bl[2][64*40];
  int bx = blockIdx.x;
  int xcd = bx & 7; int jj = bx >> 3;          // jj 0..71
  int kh = jj & 1; int sbl = jj >> 1;          // sbl 0..35
  int sb = xcd*36 + sbl;                       // 0..287
  int s0 = sb * 64;
  int n = s0 / HW; int hw0 = s0 % HW;
  int tid = threadIdx.x;
  int wave = tid >> 6, lane = tid & 63;
  int l16 = lane & 15, quad = lane >> 4;
  int mo = wave >> 1, mw = wave & 1;           // A-layout frag coords

  f32x4 acc[4][4];
  f32x4 z4 = {0.f, 0.f, 0.f, 0.f};
  #pragma unroll
  for (int i = 0; i < 4; i++)
    { acc[i][0] = z4; acc[i][1] = z4; acc[i][2] = z4; acc[i][3] = z4; }

  int s_l = tid >> 2; int cs = (tid & 3) * 8;  // B-build mapping
  int sg = s0 + s_l;

  const int itbase = kh*36;
  int4 qi; float4 gg;
  uint4 aH[4], aL[4];
  float4 tc[8];

  // ---- prologue: load regs for it 0 ----
  {
    int itg = itbase;
    int k = itg >> 3;
    qi = *(const int4*)(idx_arr + ((size_t)k*NS + sg)*4);
    gg = *(const float4*)(g_arr  + ((size_t)k*NS + sg)*4);
    int abase = ((mo*72 + itg)*2 + mw)*4;
    #pragma unroll
    for (int mi = 0; mi < 4; mi++) {
      size_t off = ((size_t)(abase + mi) << 9) + lane*8;
      aH[mi] = *(const uint4*)(A_hi + off);
      aL[mi] = *(const uint4*)(A_lo + off);
    }
    int c0k = (itg & 7) * 32;
    const float* p0 = xp + qi.x + c0k + cs;
    const float* p1 = xp + qi.y + c0k + cs;
    const float* p2 = xp + qi.z + c0k + cs;
    const float* p3 = xp + qi.w + c0k + cs;
    tc[0] = *(const float4*)(p0); tc[1] = *(const float4*)(p0 + 4);
    tc[2] = *(const float4*)(p1); tc[3] = *(const float4*)(p1 + 4);
    tc[4] = *(const float4*)(p2); tc[5] = *(const float4*)(p2 + 4);
    tc[6] = *(const float4*)(p3); tc[7] = *(const float4*)(p3 + 4);
  }

  #pragma unroll 2
  for (int it = 0; it < 36; it++) {
    int buf = it & 1;
    // ---- build current B tile from regs, write LDS (proven protocol) ----
    BW_GATHER(tc, gg, buf);
    sync_lds();
    // ---- ds_read current B fragments ----
    f16x8 bfh[4], bfl[4];
    #pragma unroll
    for (int ni = 0; ni < 4; ni++) {
      int rr = (ni*16 + l16)*40 + quad*8;
      bfh[ni] = *(const f16x8*)(&Bh[buf][rr]);
      bfl[ni] = *(const f16x8*)(&Bl[buf][rr]);
    }
    // ---- issue it+1 loads (hide under MFMA; survive lgkm-only barrier) ----
    int4 qin = qi; float4 ggn = gg;
    uint4 aHn[4], aLn[4];
    float4 tn[8];
    if (it < 35) {
      int itn = itbase + it + 1;
      if ((itn & 7) == 0) {                    // new k-window
        int k = itn >> 3;
        qin = *(const int4*)(idx_arr + ((size_t)k*NS + sg)*4);
        ggn = *(const float4*)(g_arr  + ((size_t)k*NS + sg)*4);
      }
      int abase = ((mo*72 + itn)*2 + mw)*4;
      #pragma unroll
      for (int mi = 0; mi < 4; mi++) {
        size_t off = ((size_t)(abase + mi) << 9) + lane*8;
        aHn[mi] = *(const uint4*)(A_hi + off);
        aLn[mi] = *(const uint4*)(A_lo + off);
      }
      int c0k = (itn & 7) * 32;
      const float* p0 = xp + qin.x + c0k + cs;
      const float* p1 = xp + qin.y + c0k + cs;
      const float* p2 = xp + qin.z + c0k + cs;
      const float* p3 = xp + qin.w + c0k + cs;
      tn[0] = *(const float4*)(p0); tn[1] = *(const float4*)(p0 + 4);
      tn[2] = *(const float4*)(p1); tn[3] = *(const float4*)(p1 + 4);
      tn[4] = *(const float4*)(p2); tn[5] = *(const float4*)(p2 + 4);
      tn[6] = *(const float4*)(p3); tn[7] = *(const float4*)(p3 + 4);
    }
    // ---- MFMA (current aH/aL) ----
    #pragma unroll
    for (int mi = 0; mi < 4; mi++) {
      f16x8 fh = __builtin_bit_cast(f16x8, aH[mi]);
      f16x8 fl = __builtin_bit_cast(f16x8, aL[mi]);
      #pragma unroll
      for (int ni = 0; ni < 4; ni++) {
        acc[mi][ni] = __builtin_amdgcn_mfma_f32_16x16x32_f16(fh, bfh[ni], acc[mi][ni], 0, 0, 0);
        acc[mi][ni] = __builtin_amdgcn_mfma_f32_16x16x32_f16(fh, bfl[ni], acc[mi][ni], 0, 0, 0);
        acc[mi][ni] = __builtin_amdgcn_mfma_f32_16x16x32_f16(fl, bfh[ni], acc[mi][ni], 0, 0, 0);
      }
    }
    // ---- rotate ----
    if (it < 35) {
      qi = qin; gg = ggn;
      #pragma unroll
      for (int mi = 0; mi < 4; mi++) { aH[mi] = aHn[mi]; aL[mi] = aLn[mi]; }
      #pragma unroll
      for (int j = 0; j < 8; j++) tc[j] = tn[j];
    }
  }
  // ---- epilogue: split-K accumulate ----
  #pragma unroll
  for (int mi = 0; mi < 4; mi++)
    #pragma unroll
    for (int ni = 0; ni < 4; ni++) {
      int hw = hw0 + ni*16 + l16;
      #pragma unroll
      for (int rr = 0; rr < 4; rr++) {
        int o = wave*64 + mi*16 + quad*4 + rr;
        atomicAdd(&out[(size_t)(n*OC + o)*HW + hw], acc[mi][ni][rr]);
      }
    }
}

extern "C" void kernel_launch(void* const* d_in, const int* in_sizes, int n_in,
                              void* d_out, int out_size, void* d_ws, size_t ws_size,
                              hipStream_t stream) {
  const float* x      = (const float*)d_in[0];
  const float* w_p    = (const float*)d_in[1];
  const float* b_p    = (const float*)d_in[2];
  const float* w_ad   = (const float*)d_in[3];
  const float* b_ad   = (const float*)d_in[4];
  const float* w_conv = (const float*)d_in[5];
  float* out = (float*)d_out;

  char* ws = (char*)d_ws;
  float* xp      = (float*)(ws + XP_OFF);
  u16*   A_hi    = (u16*)  (ws + AHI_OFF);
  u16*   A_lo    = (u16*)  (ws + ALO_OFF);
  u16*   A2_hi   = (u16*)  (ws + A2HI_OFF);
  u16*   A2_lo   = (u16*)  (ws + A2LO_OFF);
  float* off2    = (float*)(ws + OFF2_OFF);
  int*   idx_arr = (int*)  (ws + IDX_OFF);
  float* g_arr   = (float*)(ws + G_OFF);

  hipMemsetAsync(xp, 0, (size_t)NB*HP*HP*C*sizeof(float), stream);
  hipMemsetAsync(off2, 0, (size_t)21*NS*sizeof(float), stream);
  hipMemsetAsync(out, 0, (size_t)out_size*sizeof(float), stream);

  prep1    <<<1476, 256, 0, stream>>>(x, w_p, w_ad, w_conv, xp, A_hi, A_lo, A2_hi, A2_lo);
  conv_mfma<<<576,  256, 0, stream>>>(A2_hi, A2_lo, xp, off2);
  taps2    <<<648,  256, 0, stream>>>(off2, b_p, b_ad, idx_arr, g_arr);
  gemm_def <<<576,  256, 0, stream>>>(A_hi, A_lo, xp, idx_arr, g_arr, out);
}

// Round 5
// 201.705 us; speedup vs baseline: 1.4416x; 1.4416x over previous
//
#include <hip/hip_runtime.h>
#include <math.h>

typedef unsigned short u16;
typedef unsigned int   u32;

typedef __attribute__((ext_vector_type(8))) _Float16 f16x8;
typedef __attribute__((ext_vector_type(4))) float    f32x4;

// ---------- constants ----------
#define NB   2
#define C    256
#define H    96
#define W    96
#define HW   (H*W)          // 9216
#define HP   98
#define OC   256
#define KDIM (9*C)          // 2304
#define NS   (NB*HW)        // 18432 spatial columns

// ws layout (bytes)
#define XP_OFF    0                      // 2*98*98*256 fp32 = 19668992
#define AHI_OFF   19668992               // 256*2304 f16     = 1179648
#define ALO_OFF   20848640               // 256*2304 f16     = 1179648
#define A2HI_OFF  22028288               // 32*2304 f16      = 147456
#define A2LO_OFF  22175744               // 32*2304 f16      = 147456
#define OFF2_OFF  22323200               // 21*18432 fp32    = 1548288
#define IDX_OFF   23871488               // 9*18432*4 int    = 2654208
#define G_OFF     26525696               // 9*18432*4 fp32   = 2654208
// end 29179904

__device__ __forceinline__ u16 h2u(_Float16 h) {
  return __builtin_bit_cast(unsigned short, h);
}
__device__ __forceinline__ void split16(float v, u16& hi, u16& lo) {
  _Float16 h = (_Float16)v;        // v_cvt_f16_f32, RNE
  float r = v - (float)h;          // exact residual
  _Float16 l = (_Float16)r;
  hi = h2u(h); lo = h2u(l);
}
// LDS-only barrier: waits lgkmcnt(0) but does NOT drain vmcnt.
__device__ __forceinline__ void sync_lds() {
  asm volatile("s_waitcnt lgkmcnt(0)\n\ts_barrier" ::: "memory");
}

// ================= prep: pad_pack(0..1151) | pack_A(1152..1439) | pack_A2(1440..1475) =================
__global__ __launch_bounds__(256) void prep1(
    const float* __restrict__ x, const float* __restrict__ w_p,
    const float* __restrict__ w_ad, const float* __restrict__ w_conv,
    float* __restrict__ xp,
    u16* __restrict__ A_hi, u16* __restrict__ A_lo,
    u16* __restrict__ A2_hi, u16* __restrict__ A2_lo) {
  __shared__ float smem[64*65];
  int bx = blockIdx.x;
  int tid = threadIdx.x;

  if (bx < 1152) {
    // ---- NCHW fp32 -> padded NHWC fp32 (borders pre-zeroed by memset) ----
    int pb = bx;
    int n = pb / 576; int r = pb % 576;
    int cb = r / 144; int hwb = r % 144;
    int c0 = cb * 64, hw0 = hwb * 64;
    int ii = tid & 63; int cl4 = tid >> 6;
    #pragma unroll
    for (int r2 = 0; r2 < 16; r2++) {
      int c_l = cl4*16 + r2;
      smem[c_l*65 + ii] = x[(size_t)(n*C + c0 + c_l)*HW + hw0 + ii];
    }
    __syncthreads();
    int hw = hw0 + ii;
    int h = hw / W, w = hw % W;
    float* dst = xp + ((size_t)(n*HP + h + 1)*HP + (w + 1))*C + c0 + cl4*16;
    #pragma unroll
    for (int q = 0; q < 4; q++) {
      *(float4*)(dst + q*4) = make_float4(smem[(cl4*16 + q*4 + 0)*65 + ii],
                                          smem[(cl4*16 + q*4 + 1)*65 + ii],
                                          smem[(cl4*16 + q*4 + 2)*65 + ii],
                                          smem[(cl4*16 + q*4 + 3)*65 + ii]);
    }

  } else if (bx < 1440) {
    // ---- pack+split w_conv into MFMA-fragment-tiled A_hi/A_lo (r8/r9-proven) ----
    // e = ((((mo*72+itg)*2+mw)*4+mi)*64+lane)*8 + j holds
    //   A[o = mo*128+mw*64+mi*16+(lane&15)][kc = itg*32+(lane>>4)*8+j]
    int pb = bx - 1152;                 // 0..287
    int t = pb*256 + tid;               // 0..73727
    int e0 = t*8;
    int lane = (e0 >> 3) & 63;
    int mi   = (e0 >> 9) & 3;
    int mw   = (e0 >> 11) & 1;
    int rr   = e0 >> 12; int itg = rr % 72; int mo = rr / 72;
    int o = mo*128 + mw*64 + mi*16 + (lane & 15);
    int kcb = itg*32 + (lane >> 4)*8;
    #pragma unroll
    for (int j2 = 0; j2 < 8; j2++) {
      int kc = kcb + j2; int k = kc >> 8; int c = kc & 255;
      float a = w_conv[((size_t)o*C + c)*9 + k];
      u16 hi, lo; split16(a, hi, lo);
      A_hi[e0 + j2] = hi; A_lo[e0 + j2] = lo;
    }

  } else {
    // ---- pack+split stage-A weights into frag-tiled A2 (M=32: 0..17 w_p, 18..20 w_ad, pad 0) ----
    int pb = bx - 1440;                 // 0..35
    int t = pb*256 + tid;               // 0..9215
    int e0 = t*8;
    int lane = (e0 >> 3) & 63;
    int mi   = (e0 >> 9) & 1;
    int itg  = e0 >> 10;                // 0..71
    int o = mi*16 + (lane & 15);
    int kcb = itg*32 + (lane >> 4)*8;
    #pragma unroll
    for (int j2 = 0; j2 < 8; j2++) {
      int kc = kcb + j2; int tap = kc >> 8; int c = kc & 255;
      float a = 0.f;
      if (o < 18)       a = w_p [((size_t)o*C + c)*9 + tap];
      else if (o < 21)  a = w_ad[((size_t)(o-18)*C + c)*9 + tap];
      u16 hi, lo; split16(a, hi, lo);
      A2_hi[e0 + j2] = hi; A2_lo[e0 + j2] = lo;
    }
  }
}

// ================= stage-A conv as split-f16 MFMA: C2[21][NS] = W2 * im2col(xp) =================
// FULL 3-term split kept here: offsets feed floor()/mask discontinuities, so the
// offset path needs ~1e-5 accuracy (a 2e-4 error can flip a boundary -> 0.3 jump).
// grid 576 = xcd(8) x [kh(2) x sbl(36)]; split-K via atomicAdd into off2 (pre-zeroed).
__global__ __launch_bounds__(256) void conv_mfma(
    const u16* __restrict__ A2_hi, const u16* __restrict__ A2_lo,
    const float* __restrict__ xp, float* __restrict__ off2) {
  __shared__ u16 Bh[2][64*40];
  __shared__ u16 Bl[2][64*40];
  int bx = blockIdx.x;
  int xcd = bx & 7; int jj = bx >> 3;          // jj 0..71
  int kh = jj & 1; int sbl = jj >> 1;          // sbl 0..35
  int sb = xcd*36 + sbl;                       // 0..287
  int s0 = sb * 64;
  int tid = threadIdx.x;
  int wave = tid >> 6, lane = tid & 63;
  int l16 = lane & 15, quad = lane >> 4;

  f32x4 acc[2];
  f32x4 z4 = {0.f, 0.f, 0.f, 0.f};
  acc[0] = z4; acc[1] = z4;

  int s_l = tid >> 2; int cs = (tid & 3) * 8;  // B-build map (r7-r9 proven)
  int sg = s0 + s_l;
  int n = sg / HW; int hw = sg % HW;
  int h = hw / W, w = hw % W;
  const float* sbase = xp + ((size_t)(n*HP + h)*HP + w)*C;   // padded top-left

  for (int it = 0; it < 36; it++) {
    int itg = kh*36 + it;
    int tap = itg >> 3;
    int di = tap / 3, dj = tap % 3;
    int c0k = (itg & 7) * 32;
    // ---- A2 fragments (tiny, L2-hot; identical across waves) ----
    uint4 aH[2], aL[2];
    #pragma unroll
    for (int mi = 0; mi < 2; mi++) {
      size_t off = ((size_t)(itg*2 + mi) << 9) + lane*8;
      aH[mi] = *(const uint4*)(A2_hi + off);
      aL[mi] = *(const uint4*)(A2_lo + off);
    }
    // ---- B2 taps: one contiguous 32B read ----
    const float* p0 = sbase + (di*HP + dj)*C + c0k + cs;
    float4 ta = *(const float4*)(p0), tb = *(const float4*)(p0 + 4);
    float v[8] = {ta.x, ta.y, ta.z, ta.w, tb.x, tb.y, tb.z, tb.w};
    u16 hb[8], lb[8];
    #pragma unroll
    for (int j = 0; j < 8; j++) split16(v[j], hb[j], lb[j]);
    uint4 bph, bpl;
    bph.x = (u32)hb[0] | ((u32)hb[1] << 16); bph.y = (u32)hb[2] | ((u32)hb[3] << 16);
    bph.z = (u32)hb[4] | ((u32)hb[5] << 16); bph.w = (u32)hb[6] | ((u32)hb[7] << 16);
    bpl.x = (u32)lb[0] | ((u32)lb[1] << 16); bpl.y = (u32)lb[2] | ((u32)lb[3] << 16);
    bpl.z = (u32)lb[4] | ((u32)lb[5] << 16); bpl.w = (u32)lb[6] | ((u32)lb[7] << 16);
    int buf = it & 1;
    *(uint4*)(&Bh[buf][s_l*40 + cs]) = bph;
    *(uint4*)(&Bl[buf][s_l*40 + cs]) = bpl;
    sync_lds();
    int rr = (wave*16 + l16)*40 + quad*8;
    f16x8 bfh = *(const f16x8*)(&Bh[buf][rr]);
    f16x8 bfl = *(const f16x8*)(&Bl[buf][rr]);
    #pragma unroll
    for (int mi = 0; mi < 2; mi++) {
      f16x8 fh = __builtin_bit_cast(f16x8, aH[mi]);
      f16x8 fl = __builtin_bit_cast(f16x8, aL[mi]);
      acc[mi] = __builtin_amdgcn_mfma_f32_16x16x32_f16(fh, bfh, acc[mi], 0, 0, 0);
      acc[mi] = __builtin_amdgcn_mfma_f32_16x16x32_f16(fh, bfl, acc[mi], 0, 0, 0);
      acc[mi] = __builtin_amdgcn_mfma_f32_16x16x32_f16(fl, bfh, acc[mi], 0, 0, 0);
    }
  }
  // ---- epilogue: rows <21 accumulate into off2 ----
  int sout = s0 + wave*16 + l16;
  #pragma unroll
  for (int mi = 0; mi < 2; mi++)
    #pragma unroll
    for (int rr2 = 0; rr2 < 4; rr2++) {
      int o = mi*16 + quad*4 + rr2;
      if (o < 21)
        atomicAdd(&off2[(size_t)o*NS + sout], acc[mi][rr2]);
    }
}

// ================= bilinear taps (reads off2 directly) =================
__global__ __launch_bounds__(256) void taps2(
    const float* __restrict__ off2, const float* __restrict__ b_p,
    const float* __restrict__ b_ad,
    int* __restrict__ idx_arr, float* __restrict__ g_arr) {
  int e = blockIdx.x * 256 + threadIdx.x;      // < 9*18432 = 165888
  int k = e / NS; int s = e % NS;
  int n = s / HW; int hw = s % HW;
  int h = hw / W, w = hw % W;
  float offx = off2[(size_t)k*NS + s]            + b_p[k];
  float offy = off2[(size_t)(k+9)*NS + s]        + b_p[k+9];
  float za   = off2[(size_t)(18 + (k%3))*NS + s] + b_ad[k % 3];
  float a2 = 2.0f / (1.0f + expf(za));         // (1-sigmoid)*DIL

  float ri = (float)(k / 3) - 1.0f, rj = (float)(k % 3) - 1.0f;
  float px = (float)(h + 1) + ri + offx + a2 * ri;
  float py = (float)(w + 1) + rj + offy + a2 * rj;
  float fx = floorf(px), fy = floorf(py);
  int qltx = min(max((int)fx, 0), 97);
  int qlty = min(max((int)fy, 0), 97);
  int qrbx = min(max((int)fx + 1, 0), 97);
  int qrby = min(max((int)fy + 1, 0), 97);
  bool mx = (px < 1.0f) || (px > 96.0f);
  bool my = (py < 1.0f) || (py > 96.0f);
  float pxm = mx ? fx : px;
  float pym = my ? fy : py;
  pxm = fminf(fmaxf(pxm, 0.f), 97.f);
  pym = fminf(fmaxf(pym, 0.f), 97.f);
  float glx = 1.0f + ((float)qltx - pxm);
  float grx = 1.0f - ((float)qrbx - pxm);
  float gly = 1.0f + ((float)qlty - pym);
  float gry = 1.0f - ((float)qrby - pym);
  int base = n * HP * HP * C;
  int4 qi;
  qi.x = base + (qltx*HP + qlty)*C;   // lt
  qi.y = base + (qrbx*HP + qrby)*C;   // rb
  qi.z = base + (qltx*HP + qrby)*C;   // lb
  qi.w = base + (qrbx*HP + qlty)*C;   // rt
  float4 gg = make_float4(glx*gly, grx*gry, glx*gry, grx*gly);
  *(int4*)(idx_arr + (size_t)e*4) = qi;
  *(float4*)(g_arr  + (size_t)e*4) = gg;
}

// ================= fused gather + PURE-F16 MFMA GEMM, M=256 (r9 skeleton) =================
// The output GEMM is smooth in its inputs (no floor/mask discontinuity), and the
// error budget allows plain f16: delta_std = sqrt(2304)*sqrt((0.02*5e-4)^2+(1e-5)^2)
// ~= 7e-4 << measured 0.0156 absmax << 0.0703 threshold. So: drop A_lo and B_lo.
// 16 MFMA/iter (was 48), half the LDS traffic, no split16 in the build.
// grid 576 = xcd(8) x [kh(2) x sbl(36)]; split-K2 via atomicAdd into out (pre-zeroed).
__global__ __launch_bounds__(256) void gemm_def(
    const u16* __restrict__ A_hi,
    const float* __restrict__ xp,
    const int* __restrict__ idx_arr, const float* __restrict__ g_arr,
    float* __restrict__ out) {
  __shared__ u16 Bh[2][64*40];
  int bx = blockIdx.x;
  int xcd = bx & 7; int jj = bx >> 3;          // jj 0..71
  int kh = jj & 1; int sbl = jj >> 1;          // sbl 0..35
  int sb = xcd*36 + sbl;                       // 0..287
  int s0 = sb * 64;
  int n = s0 / HW; int hw0 = s0 % HW;
  int tid = threadIdx.x;
  int wave = tid >> 6, lane = tid & 63;
  int l16 = lane & 15, quad = lane >> 4;
  int mo = wave >> 1, mw = wave & 1;           // A-layout frag coords

  f32x4 acc[4][4];
  f32x4 z4 = {0.f, 0.f, 0.f, 0.f};
  #pragma unroll
  for (int i = 0; i < 4; i++)
    { acc[i][0] = z4; acc[i][1] = z4; acc[i][2] = z4; acc[i][3] = z4; }

  int s_l = tid >> 2; int cs = (tid & 3) * 8;  // B-build mapping
  int sg = s0 + s_l;

  int4 qi; float4 gg;
  for (int it = 0; it < 36; it++) {
    int itg = kh*36 + it;
    int c0k = (itg & 7) * 32;
    if (it == 0 || (itg & 7) == 0) {           // qi/g hoisted per k-window
      int k = itg >> 3;
      qi = *(const int4*)(idx_arr + ((size_t)k*NS + sg)*4);
      gg = *(const float4*)(g_arr  + ((size_t)k*NS + sg)*4);
    }
    // ---- A fragments direct from global (coalesced 16B/lane, L2-hot), hi only ----
    uint4 aH[4];
    int abase = ((mo*72 + itg)*2 + mw)*4;
    #pragma unroll
    for (int mi = 0; mi < 4; mi++) {
      size_t off = ((size_t)(abase + mi) << 9) + lane*8;
      aH[mi] = *(const uint4*)(A_hi + off);
    }
    // ---- taps ----
    const float* p0 = xp + qi.x + c0k + cs;
    const float* p1 = xp + qi.y + c0k + cs;
    const float* p2 = xp + qi.z + c0k + cs;
    const float* p3 = xp + qi.w + c0k + cs;
    float4 t0a = *(const float4*)(p0), t0b = *(const float4*)(p0 + 4);
    float4 t1a = *(const float4*)(p1), t1b = *(const float4*)(p1 + 4);
    float4 t2a = *(const float4*)(p2), t2b = *(const float4*)(p2 + 4);
    float4 t3a = *(const float4*)(p3), t3b = *(const float4*)(p3 + 4);
    float v[8];
    v[0] = gg.x*t0a.x + gg.y*t1a.x + gg.z*t2a.x + gg.w*t3a.x;
    v[1] = gg.x*t0a.y + gg.y*t1a.y + gg.z*t2a.y + gg.w*t3a.y;
    v[2] = gg.x*t0a.z + gg.y*t1a.z + gg.z*t2a.z + gg.w*t3a.z;
    v[3] = gg.x*t0a.w + gg.y*t1a.w + gg.z*t2a.w + gg.w*t3a.w;
    v[4] = gg.x*t0b.x + gg.y*t1b.x + gg.z*t2b.x + gg.w*t3b.x;
    v[5] = gg.x*t0b.y + gg.y*t1b.y + gg.z*t2b.y + gg.w*t3b.y;
    v[6] = gg.x*t0b.z + gg.y*t1b.z + gg.z*t2b.z + gg.w*t3b.z;
    v[7] = gg.x*t0b.w + gg.y*t1b.w + gg.z*t2b.w + gg.w*t3b.w;
    u16 hb[8];
    #pragma unroll
    for (int j = 0; j < 8; j++) hb[j] = h2u((_Float16)v[j]);
    uint4 bph;
    bph.x = (u32)hb[0] | ((u32)hb[1] << 16); bph.y = (u32)hb[2] | ((u32)hb[3] << 16);
    bph.z = (u32)hb[4] | ((u32)hb[5] << 16); bph.w = (u32)hb[6] | ((u32)hb[7] << 16);
    int buf = it & 1;
    *(uint4*)(&Bh[buf][s_l*40 + cs]) = bph;
    sync_lds();   // single barrier/iter (proven protocol)
    f16x8 bfh[4];
    #pragma unroll
    for (int ni = 0; ni < 4; ni++) {
      int rr = (ni*16 + l16)*40 + quad*8;
      bfh[ni] = *(const f16x8*)(&Bh[buf][rr]);
    }
    #pragma unroll
    for (int mi = 0; mi < 4; mi++) {
      f16x8 fh = __builtin_bit_cast(f16x8, aH[mi]);
      #pragma unroll
      for (int ni = 0; ni < 4; ni++) {
        acc[mi][ni] = __builtin_amdgcn_mfma_f32_16x16x32_f16(fh, bfh[ni], acc[mi][ni], 0, 0, 0);
      }
    }
  }
  // ---- epilogue: split-K accumulate ----
  #pragma unroll
  for (int mi = 0; mi < 4; mi++)
    #pragma unroll
    for (int ni = 0; ni < 4; ni++) {
      int hw = hw0 + ni*16 + l16;
      #pragma unroll
      for (int rr = 0; rr < 4; rr++) {
        int o = wave*64 + mi*16 + quad*4 + rr;
        atomicAdd(&out[(size_t)(n*OC + o)*HW + hw], acc[mi][ni][rr]);
      }
    }
}

extern "C" void kernel_launch(void* const* d_in, const int* in_sizes, int n_in,
                              void* d_out, int out_size, void* d_ws, size_t ws_size,
                              hipStream_t stream) {
  const float* x      = (const float*)d_in[0];
  const float* w_p    = (const float*)d_in[1];
  const float* b_p    = (const float*)d_in[2];
  const float* w_ad   = (const float*)d_in[3];
  const float* b_ad   = (const float*)d_in[4];
  const float* w_conv = (const float*)d_in[5];
  float* out = (float*)d_out;

  char* ws = (char*)d_ws;
  float* xp      = (float*)(ws + XP_OFF);
  u16*   A_hi    = (u16*)  (ws + AHI_OFF);
  u16*   A_lo    = (u16*)  (ws + ALO_OFF);
  u16*   A2_hi   = (u16*)  (ws + A2HI_OFF);
  u16*   A2_lo   = (u16*)  (ws + A2LO_OFF);
  float* off2    = (float*)(ws + OFF2_OFF);
  int*   idx_arr = (int*)  (ws + IDX_OFF);
  float* g_arr   = (float*)(ws + G_OFF);

  hipMemsetAsync(xp, 0, (size_t)NB*HP*HP*C*sizeof(float), stream);
  hipMemsetAsync(off2, 0, (size_t)21*NS*sizeof(float), stream);
  hipMemsetAsync(out, 0, (size_t)out_size*sizeof(float), stream);

  prep1    <<<1476, 256, 0, stream>>>(x, w_p, w_ad, w_conv, xp, A_hi, A_lo, A2_hi, A2_lo);
  conv_mfma<<<576,  256, 0, stream>>>(A2_hi, A2_lo, xp, off2);
  taps2    <<<648,  256, 0, stream>>>(off2, b_p, b_ad, idx_arr, g_arr);
  gemm_def <<<576,  256, 0, stream>>>(A_hi, xp, idx_arr, g_arr, out);
}